// Round 2
// baseline (373.660 us; speedup 1.0000x reference)
//
#include <hip/hip_runtime.h>
#include <hip/hip_bf16.h>
#include <stdint.h>

#define Nn 8192
#define Dd 256
#define TWO_N 16384
#define INV_TAU 2.0f

typedef unsigned short u16;
typedef __bf16 bf16x8 __attribute__((ext_vector_type(8)));
typedef float f32x4 __attribute__((ext_vector_type(4)));

typedef const __attribute__((address_space(1))) void* gas_ptr;
typedef __attribute__((address_space(3))) void* las_ptr;

__device__ __forceinline__ void async_copy16(const void* g, void* l) {
  __builtin_amdgcn_global_load_lds((gas_ptr)g, (las_ptr)l, 16, 0, 0);
}

__device__ __forceinline__ u16 f2bf(float x) {
  uint32_t u = __float_as_uint(x);
  u = u + 0x7fffu + ((u >> 16) & 1u);
  return (u16)(u >> 16);
}
__device__ __forceinline__ float bf2f(u16 u) {
  return __uint_as_float(((uint32_t)u) << 16);
}

// ---------------- cast fp32 -> bf16 (4 elems/thread) ----------------
__global__ void cast4_kernel(const float* __restrict__ src, u16* __restrict__ dst, int n4) {
  int i = blockIdx.x * 256 + threadIdx.x;
  if (i < n4) {
    float4 v = ((const float4*)src)[i];
    ushort4 o;
    o.x = f2bf(v.x); o.y = f2bf(v.y); o.z = f2bf(v.z); o.w = f2bf(v.w);
    ((ushort4*)dst)[i] = o;
  }
}

// ---------------- MLP layer GEMM: out[m,n] = sum_k A[m,k]*B[n,k] + bias[n] ----
// LDS layout: granule p of row r holds global granule (p ^ (r&7)) -> bank-conflict-free
// EPI 0: elu -> bf16 store ; EPI 1: plain -> f32 store
template<int EPI>
__global__ __launch_bounds__(256)
void mfma_gemm_nt(const u16* __restrict__ A, const u16* __restrict__ B,
                  const float* __restrict__ bias, void* __restrict__ outp,
                  int K, int Ncols) {
  __shared__ __bf16 sA[128 * 64];
  __shared__ __bf16 sB[128 * 64];
  const int i0 = blockIdx.x * 128;
  const int j0 = blockIdx.y * 128;
  const int t = threadIdx.x;
  const int lane = t & 63, wave = t >> 6;
  const int wm = (wave >> 1) * 64, wn = (wave & 1) * 64;
  const int fr = lane >> 4, fc = lane & 15;
  const int sw = fc & 7;  // read-side xor key (row & 7 == fc & 7)

  f32x4 acc[4][4];
#pragma unroll
  for (int a = 0; a < 4; a++)
#pragma unroll
    for (int b = 0; b < 4; b++) acc[a][b] = (f32x4){0.f, 0.f, 0.f, 0.f};

  const u16* Ag = A + (size_t)i0 * K;
  const u16* Bg = B + (size_t)j0 * K;

  for (int k0 = 0; k0 < K; k0 += 64) {
    __syncthreads();
#pragma unroll
    for (int it = 0; it < 4; ++it) {
      int c = t + 256 * it;
      int row = c >> 3;
      int kc = ((c & 7) ^ (row & 7)) * 8;  // swizzled global granule
      async_copy16(Ag + (size_t)row * K + k0 + kc, (void*)&sA[c * 8]);
      async_copy16(Bg + (size_t)row * K + k0 + kc, (void*)&sB[c * 8]);
    }
    __syncthreads();
#pragma unroll
    for (int ks = 0; ks < 2; ++ks) {
      bf16x8 af[4], bfr[4];
#pragma unroll
      for (int mi = 0; mi < 4; mi++)
        af[mi] = *(const bf16x8*)&sA[(wm + mi * 16 + fc) * 64 + (((ks * 4 + fr) ^ sw) * 8)];
#pragma unroll
      for (int ni = 0; ni < 4; ni++)
        bfr[ni] = *(const bf16x8*)&sB[(wn + ni * 16 + fc) * 64 + (((ks * 4 + fr) ^ sw) * 8)];
#pragma unroll
      for (int mi = 0; mi < 4; mi++)
#pragma unroll
        for (int ni = 0; ni < 4; ni++)
          acc[mi][ni] = __builtin_amdgcn_mfma_f32_16x16x32_bf16(af[mi], bfr[ni], acc[mi][ni], 0, 0, 0);
    }
  }

#pragma unroll
  for (int mi = 0; mi < 4; mi++) {
#pragma unroll
    for (int ni = 0; ni < 4; ni++) {
      int col = j0 + wn + ni * 16 + fc;
      float bv = bias[col];
#pragma unroll
      for (int r = 0; r < 4; r++) {
        int row = i0 + wm + mi * 16 + fr * 4 + r;
        float v = acc[mi][ni][r] + bv;
        if (EPI == 0) {
          v = v > 0.f ? v : (__expf(v) - 1.f);
          ((u16*)outp)[(size_t)row * Ncols + col] = f2bf(v);
        } else {
          ((float*)outp)[(size_t)row * Ncols + col] = v;
        }
      }
    }
  }
}

// ---------------- row-normalize -> bf16 M, plus snorm = ||bf16(n)||^2 ----------
__global__ void normalize_rows(const float* __restrict__ H, u16* __restrict__ Mb,
                               float* __restrict__ snorm) {
  int row = blockIdx.x, lane = threadIdx.x;
  float4 v = ((const float4*)(H + (size_t)row * 256))[lane];
  float ss = v.x * v.x + v.y * v.y + v.z * v.z + v.w * v.w;
#pragma unroll
  for (int off = 32; off; off >>= 1) ss += __shfl_xor(ss, off, 64);
  float rn = 1.f / fmaxf(sqrtf(ss), 1e-12f);
  ushort4 o;
  o.x = f2bf(v.x * rn); o.y = f2bf(v.y * rn); o.z = f2bf(v.z * rn); o.w = f2bf(v.w * rn);
  ((ushort4*)(Mb + (size_t)row * 256))[lane] = o;
  float a0 = bf2f(o.x), a1 = bf2f(o.y), a2 = bf2f(o.z), a3 = bf2f(o.w);
  float s2 = a0 * a0 + a1 * a1 + a2 * a2 + a3 * a3;
#pragma unroll
  for (int off = 32; off; off >>= 1) s2 += __shfl_xor(s2, off, 64);
  if (lane == 0) snorm[row] = s2;
}

// ---------------- fused Gram-exp-rowsum --------------------------------------
// block: 128 rows (blockIdx.x) x 1024 cols chunk (blockIdx.y)
// per-lane row partials accumulated across j-tiles; one 16-lane reduce at end
__global__ __launch_bounds__(256)
void gram_rowsum(const u16* __restrict__ Mb, float* __restrict__ rsum) {
  __shared__ __bf16 sA[128 * 64];
  __shared__ __bf16 sB[128 * 64];
  const int t = threadIdx.x;
  const int lane = t & 63, wave = t >> 6;
  const int wm = (wave >> 1) * 64, wn = (wave & 1) * 64;
  const int fr = lane >> 4, fc = lane & 15;
  const int sw = fc & 7;
  const int i0 = blockIdx.x * 128;
  const int jbase = blockIdx.y * 1024;
  const u16* Ag = Mb + (size_t)i0 * 256;

  float rowacc[4][4];
#pragma unroll
  for (int a = 0; a < 4; a++)
#pragma unroll
    for (int r = 0; r < 4; r++) rowacc[a][r] = 0.f;

  for (int jt = 0; jt < 8; ++jt) {
    const u16* Bg = Mb + (size_t)(jbase + jt * 128) * 256;
    f32x4 acc[4][4];
#pragma unroll
    for (int a = 0; a < 4; a++)
#pragma unroll
      for (int b = 0; b < 4; b++) acc[a][b] = (f32x4){0.f, 0.f, 0.f, 0.f};

    for (int k0 = 0; k0 < 256; k0 += 64) {
      __syncthreads();
#pragma unroll
      for (int it = 0; it < 4; ++it) {
        int c = t + 256 * it;
        int row = c >> 3;
        int kc = ((c & 7) ^ (row & 7)) * 8;
        async_copy16(Ag + (size_t)row * 256 + k0 + kc, (void*)&sA[c * 8]);
        async_copy16(Bg + (size_t)row * 256 + k0 + kc, (void*)&sB[c * 8]);
      }
      __syncthreads();
#pragma unroll
      for (int ks = 0; ks < 2; ++ks) {
        bf16x8 af[4], bfr[4];
#pragma unroll
        for (int mi = 0; mi < 4; mi++)
          af[mi] = *(const bf16x8*)&sA[(wm + mi * 16 + fc) * 64 + (((ks * 4 + fr) ^ sw) * 8)];
#pragma unroll
        for (int ni = 0; ni < 4; ni++)
          bfr[ni] = *(const bf16x8*)&sB[(wn + ni * 16 + fc) * 64 + (((ks * 4 + fr) ^ sw) * 8)];
#pragma unroll
        for (int mi = 0; mi < 4; mi++)
#pragma unroll
          for (int ni = 0; ni < 4; ni++)
            acc[mi][ni] = __builtin_amdgcn_mfma_f32_16x16x32_bf16(af[mi], bfr[ni], acc[mi][ni], 0, 0, 0);
      }
    }

    // epilogue: exp(2*s), accumulate per-lane row partials (no cross-lane ops here)
#pragma unroll
    for (int mi = 0; mi < 4; mi++)
#pragma unroll
      for (int ni = 0; ni < 4; ni++) {
        rowacc[mi][0] += __expf(acc[mi][ni][0] * INV_TAU);
        rowacc[mi][1] += __expf(acc[mi][ni][1] * INV_TAU);
        rowacc[mi][2] += __expf(acc[mi][ni][2] * INV_TAU);
        rowacc[mi][3] += __expf(acc[mi][ni][3] * INV_TAU);
      }
  }

  // one cross-lane reduce over the 16 fc lanes (same row), then atomic add
#pragma unroll
  for (int mi = 0; mi < 4; mi++)
#pragma unroll
    for (int r = 0; r < 4; r++) {
      float v = rowacc[mi][r];
#pragma unroll
      for (int off = 1; off < 16; off <<= 1) v += __shfl_xor(v, off, 16);
      rowacc[mi][r] = v;
    }

  if (fc == 0) {
#pragma unroll
    for (int mi = 0; mi < 4; mi++)
#pragma unroll
      for (int r = 0; r < 4; r++)
        atomicAdd(&rsum[i0 + wm + mi * 16 + fr * 4 + r], rowacc[mi][r]);
  }
}

// ---------------- final loss --------------------------------------------------
__global__ void final_loss(const u16* __restrict__ Mb, const float* __restrict__ rsum,
                           const float* __restrict__ snorm, float* __restrict__ out) {
  int i = blockIdx.x, lane = threadIdx.x;
  ushort4 ua = ((const ushort4*)(Mb + (size_t)i * 256))[lane];
  ushort4 ub = ((const ushort4*)(Mb + (size_t)(Nn + i) * 256))[lane];
  float d = bf2f(ua.x) * bf2f(ub.x) + bf2f(ua.y) * bf2f(ub.y) +
            bf2f(ua.z) * bf2f(ub.z) + bf2f(ua.w) * bf2f(ub.w);
#pragma unroll
  for (int off = 32; off; off >>= 1) d += __shfl_xor(d, off, 64);
  if (lane == 0) {
    float den1 = rsum[i] - __expf(snorm[i] * INV_TAU);
    float den2 = rsum[Nn + i] - __expf(snorm[Nn + i] * INV_TAU);
    out[i] = 0.5f * (logf(den1) + logf(den2)) - d * INV_TAU;
  }
}

extern "C" void kernel_launch(void* const* d_in, const int* in_sizes, int n_in,
                              void* d_out, int out_size, void* d_ws, size_t ws_size,
                              hipStream_t stream) {
  const float* z1 = (const float*)d_in[0];
  const float* z2 = (const float*)d_in[1];
  const float* W1 = (const float*)d_in[2];
  const float* b1 = (const float*)d_in[3];
  const float* W2 = (const float*)d_in[4];
  const float* b2 = (const float*)d_in[5];
  float* out = (float*)d_out;

  char* ws = (char*)d_ws;
  u16*   Zb    = (u16*)(ws);                          // 8 MB (reused as Mb)
  u16*   H1b   = (u16*)(ws + (8u << 20));             // 8 MB
  float* Hf    = (float*)(ws + (16u << 20));          // 16 MB
  u16*   W1b   = (u16*)(ws + (32u << 20));            // 128 KB
  u16*   W2b   = (u16*)(ws + (32u << 20) + 131072);   // 128 KB
  float* rsum  = (float*)(ws + (32u << 20) + 262144); // 64 KB
  float* snorm = (float*)(ws + (32u << 20) + 262144 + 65536); // 64 KB
  u16*   Mb    = Zb;  // Zb dead after layer 1

  int n4z = Nn * Dd / 4;
  cast4_kernel<<<(n4z + 255) / 256, 256, 0, stream>>>(z1, Zb, n4z);
  cast4_kernel<<<(n4z + 255) / 256, 256, 0, stream>>>(z2, Zb + (size_t)Nn * Dd, n4z);
  int n4w = 256 * 256 / 4;
  cast4_kernel<<<(n4w + 255) / 256, 256, 0, stream>>>(W1, W1b, n4w);
  cast4_kernel<<<(n4w + 255) / 256, 256, 0, stream>>>(W2, W2b, n4w);

  // layer 1: elu(Z @ W1^T + b1) -> bf16
  mfma_gemm_nt<0><<<dim3(TWO_N / 128, 2), 256, 0, stream>>>(Zb, W1b, b1, (void*)H1b, 256, 256);
  // layer 2: H1 @ W2^T + b2 -> f32
  mfma_gemm_nt<1><<<dim3(TWO_N / 128, 2), 256, 0, stream>>>(H1b, W2b, b2, (void*)Hf, 256, 256);

  normalize_rows<<<TWO_N, 64, 0, stream>>>(Hf, Mb, snorm);

  hipMemsetAsync(rsum, 0, TWO_N * sizeof(float), stream);
  gram_rowsum<<<dim3(TWO_N / 128, 16), 256, 0, stream>>>(Mb, rsum);

  final_loss<<<Nn, 64, 0, stream>>>(Mb, rsum, snorm, out);
}

// Round 3
// 277.781 us; speedup vs baseline: 1.3452x; 1.3452x over previous
//
#include <hip/hip_runtime.h>
#include <hip/hip_bf16.h>
#include <stdint.h>

#define Nn 8192
#define Dd 256
#define TWO_N 16384
#define INV_TAU 2.0f

typedef unsigned short u16;
typedef __bf16 bf16x8 __attribute__((ext_vector_type(8)));
typedef float f32x4 __attribute__((ext_vector_type(4)));

typedef const __attribute__((address_space(1))) void* gas_ptr;
typedef __attribute__((address_space(3))) void* las_ptr;

__device__ __forceinline__ void async_copy16(const void* g, void* l) {
  __builtin_amdgcn_global_load_lds((gas_ptr)g, (las_ptr)l, 16, 0, 0);
}

__device__ __forceinline__ u16 f2bf(float x) {
  uint32_t u = __float_as_uint(x);
  u = u + 0x7fffu + ((u >> 16) & 1u);
  return (u16)(u >> 16);
}
__device__ __forceinline__ float bf2f(u16 u) {
  return __uint_as_float(((uint32_t)u) << 16);
}

// ---------------- cast fp32 -> bf16 (4 elems/thread) ----------------
__global__ void cast4_kernel(const float* __restrict__ src, u16* __restrict__ dst, int n4) {
  int i = blockIdx.x * 256 + threadIdx.x;
  if (i < n4) {
    float4 v = ((const float4*)src)[i];
    ushort4 o;
    o.x = f2bf(v.x); o.y = f2bf(v.y); o.z = f2bf(v.z); o.w = f2bf(v.w);
    ((ushort4*)dst)[i] = o;
  }
}

// ---------------- MLP layer GEMM: out[m,n] = sum_k A[m,k]*B[n,k] + bias[n] ----
// LDS layout: granule p of row r holds global granule (p ^ (r&7)) -> conflict-free
template<int EPI>
__global__ __launch_bounds__(256)
void mfma_gemm_nt(const u16* __restrict__ A, const u16* __restrict__ B,
                  const float* __restrict__ bias, void* __restrict__ outp,
                  int K, int Ncols) {
  __shared__ __bf16 sA[128 * 64];
  __shared__ __bf16 sB[128 * 64];
  const int i0 = blockIdx.x * 128;
  const int j0 = blockIdx.y * 128;
  const int t = threadIdx.x;
  const int lane = t & 63, wave = t >> 6;
  const int wm = (wave >> 1) * 64, wn = (wave & 1) * 64;
  const int fr = lane >> 4, fc = lane & 15;
  const int sw = fc & 7;

  f32x4 acc[4][4];
#pragma unroll
  for (int a = 0; a < 4; a++)
#pragma unroll
    for (int b = 0; b < 4; b++) acc[a][b] = (f32x4){0.f, 0.f, 0.f, 0.f};

  const u16* Ag = A + (size_t)i0 * K;
  const u16* Bg = B + (size_t)j0 * K;

  for (int k0 = 0; k0 < K; k0 += 64) {
    __syncthreads();
#pragma unroll
    for (int it = 0; it < 4; ++it) {
      int c = t + 256 * it;
      int row = c >> 3;
      int kc = ((c & 7) ^ (row & 7)) * 8;
      async_copy16(Ag + (size_t)row * K + k0 + kc, (void*)&sA[c * 8]);
      async_copy16(Bg + (size_t)row * K + k0 + kc, (void*)&sB[c * 8]);
    }
    __syncthreads();
#pragma unroll
    for (int ks = 0; ks < 2; ++ks) {
      bf16x8 af[4], bfr[4];
#pragma unroll
      for (int mi = 0; mi < 4; mi++)
        af[mi] = *(const bf16x8*)&sA[(wm + mi * 16 + fc) * 64 + (((ks * 4 + fr) ^ sw) * 8)];
#pragma unroll
      for (int ni = 0; ni < 4; ni++)
        bfr[ni] = *(const bf16x8*)&sB[(wn + ni * 16 + fc) * 64 + (((ks * 4 + fr) ^ sw) * 8)];
#pragma unroll
      for (int mi = 0; mi < 4; mi++)
#pragma unroll
        for (int ni = 0; ni < 4; ni++)
          acc[mi][ni] = __builtin_amdgcn_mfma_f32_16x16x32_bf16(af[mi], bfr[ni], acc[mi][ni], 0, 0, 0);
    }
  }

#pragma unroll
  for (int mi = 0; mi < 4; mi++) {
#pragma unroll
    for (int ni = 0; ni < 4; ni++) {
      int col = j0 + wn + ni * 16 + fc;
      float bv = bias[col];
#pragma unroll
      for (int r = 0; r < 4; r++) {
        int row = i0 + wm + mi * 16 + fr * 4 + r;
        float v = acc[mi][ni][r] + bv;
        if (EPI == 0) {
          v = v > 0.f ? v : (__expf(v) - 1.f);
          ((u16*)outp)[(size_t)row * Ncols + col] = f2bf(v);
        } else {
          ((float*)outp)[(size_t)row * Ncols + col] = v;
        }
      }
    }
  }
}

// ---------------- row-normalize -> bf16 M, plus snorm = ||bf16(n)||^2 ----------
__global__ void normalize_rows(const float* __restrict__ H, u16* __restrict__ Mb,
                               float* __restrict__ snorm) {
  int row = blockIdx.x, lane = threadIdx.x;
  float4 v = ((const float4*)(H + (size_t)row * 256))[lane];
  float ss = v.x * v.x + v.y * v.y + v.z * v.z + v.w * v.w;
#pragma unroll
  for (int off = 32; off; off >>= 1) ss += __shfl_xor(ss, off, 64);
  float rn = 1.f / fmaxf(sqrtf(ss), 1e-12f);
  ushort4 o;
  o.x = f2bf(v.x * rn); o.y = f2bf(v.y * rn); o.z = f2bf(v.z * rn); o.w = f2bf(v.w * rn);
  ((ushort4*)(Mb + (size_t)row * 256))[lane] = o;
  float a0 = bf2f(o.x), a1 = bf2f(o.y), a2 = bf2f(o.z), a3 = bf2f(o.w);
  float s2 = a0 * a0 + a1 * a1 + a2 * a2 + a3 * a3;
#pragma unroll
  for (int off = 32; off; off >>= 1) s2 += __shfl_xor(s2, off, 64);
  if (lane == 0) snorm[row] = s2;
}

// ---------------- symmetric Gram-exp-rowsum ----------------------------------
// One 128x128 tile-pair per block; only upper triangle (i_t <= j_t) computed.
// Off-diagonal tiles contribute row-sums to rows I and col-sums to rows J.
// Balanced mapping: superrow s owns row s (128-s tiles) + row 127-s (s+1 tiles).
__global__ __launch_bounds__(256)
void gram_sym(const u16* __restrict__ Mb, float* __restrict__ rsum) {
  __shared__ __bf16 sA[128 * 64];
  __shared__ __bf16 sB[128 * 64];
  const int t = threadIdx.x;
  const int lane = t & 63, wave = t >> 6;
  const int wm = (wave >> 1) * 64, wn = (wave & 1) * 64;
  const int fr = lane >> 4, fc = lane & 15;
  const int sw = fc & 7;

  const int s = blockIdx.y, p = blockIdx.x;
  int i_t, j_t;
  if (p < 128 - s) { i_t = s;       j_t = s + p; }
  else             { i_t = 127 - s; j_t = 127 - s + (p - (128 - s)); }
  const int i0 = i_t * 128, j0 = j_t * 128;
  const u16* Ag = Mb + (size_t)i0 * 256;
  const u16* Bg = Mb + (size_t)j0 * 256;

  f32x4 acc[4][4];
#pragma unroll
  for (int a = 0; a < 4; a++)
#pragma unroll
    for (int b = 0; b < 4; b++) acc[a][b] = (f32x4){0.f, 0.f, 0.f, 0.f};

  for (int k0 = 0; k0 < 256; k0 += 64) {
    __syncthreads();
#pragma unroll
    for (int it = 0; it < 4; ++it) {
      int c = t + 256 * it;
      int row = c >> 3;
      int kc = ((c & 7) ^ (row & 7)) * 8;
      async_copy16(Ag + (size_t)row * 256 + k0 + kc, (void*)&sA[c * 8]);
      async_copy16(Bg + (size_t)row * 256 + k0 + kc, (void*)&sB[c * 8]);
    }
    __syncthreads();
#pragma unroll
    for (int ks = 0; ks < 2; ++ks) {
      bf16x8 af[4], bfr[4];
#pragma unroll
      for (int mi = 0; mi < 4; mi++)
        af[mi] = *(const bf16x8*)&sA[(wm + mi * 16 + fc) * 64 + (((ks * 4 + fr) ^ sw) * 8)];
#pragma unroll
      for (int ni = 0; ni < 4; ni++)
        bfr[ni] = *(const bf16x8*)&sB[(wn + ni * 16 + fc) * 64 + (((ks * 4 + fr) ^ sw) * 8)];
#pragma unroll
      for (int mi = 0; mi < 4; mi++)
#pragma unroll
        for (int ni = 0; ni < 4; ni++)
          acc[mi][ni] = __builtin_amdgcn_mfma_f32_16x16x32_bf16(af[mi], bfr[ni], acc[mi][ni], 0, 0, 0);
    }
  }

  // epilogue: e = exp(2*s); row-sums -> rows I; col-sums -> rows J (if i!=j)
  float colp[4] = {0.f, 0.f, 0.f, 0.f};
#pragma unroll
  for (int mi = 0; mi < 4; mi++) {
    float rowp0 = 0.f, rowp1 = 0.f, rowp2 = 0.f, rowp3 = 0.f;
#pragma unroll
    for (int ni = 0; ni < 4; ni++) {
      float e0 = __expf(acc[mi][ni][0] * INV_TAU);
      float e1 = __expf(acc[mi][ni][1] * INV_TAU);
      float e2 = __expf(acc[mi][ni][2] * INV_TAU);
      float e3 = __expf(acc[mi][ni][3] * INV_TAU);
      rowp0 += e0; rowp1 += e1; rowp2 += e2; rowp3 += e3;
      colp[ni] += e0 + e1 + e2 + e3;
    }
    // reduce across the 16 fc lanes (same rows)
#pragma unroll
    for (int off = 1; off < 16; off <<= 1) {
      rowp0 += __shfl_xor(rowp0, off, 16);
      rowp1 += __shfl_xor(rowp1, off, 16);
      rowp2 += __shfl_xor(rowp2, off, 16);
      rowp3 += __shfl_xor(rowp3, off, 16);
    }
    if (fc == 0) {
      int rbase = i0 + wm + mi * 16 + fr * 4;
      atomicAdd(&rsum[rbase + 0], rowp0);
      atomicAdd(&rsum[rbase + 1], rowp1);
      atomicAdd(&rsum[rbase + 2], rowp2);
      atomicAdd(&rsum[rbase + 3], rowp3);
    }
  }

  if (i_t != j_t) {
    // col-sums: reduce across fr lanes (xor 16, 32 within the 64-lane wave)
#pragma unroll
    for (int ni = 0; ni < 4; ni++) {
      float v = colp[ni];
      v += __shfl_xor(v, 16, 64);
      v += __shfl_xor(v, 32, 64);
      if (fr == 0) atomicAdd(&rsum[j0 + wn + ni * 16 + fc], v);
    }
  }
}

// ---------------- final loss --------------------------------------------------
__global__ void final_loss(const u16* __restrict__ Mb, const float* __restrict__ rsum,
                           const float* __restrict__ snorm, float* __restrict__ out) {
  int i = blockIdx.x, lane = threadIdx.x;
  ushort4 ua = ((const ushort4*)(Mb + (size_t)i * 256))[lane];
  ushort4 ub = ((const ushort4*)(Mb + (size_t)(Nn + i) * 256))[lane];
  float d = bf2f(ua.x) * bf2f(ub.x) + bf2f(ua.y) * bf2f(ub.y) +
            bf2f(ua.z) * bf2f(ub.z) + bf2f(ua.w) * bf2f(ub.w);
#pragma unroll
  for (int off = 32; off; off >>= 1) d += __shfl_xor(d, off, 64);
  if (lane == 0) {
    float den1 = rsum[i] - __expf(snorm[i] * INV_TAU);
    float den2 = rsum[Nn + i] - __expf(snorm[Nn + i] * INV_TAU);
    out[i] = 0.5f * (logf(den1) + logf(den2)) - d * INV_TAU;
  }
}

extern "C" void kernel_launch(void* const* d_in, const int* in_sizes, int n_in,
                              void* d_out, int out_size, void* d_ws, size_t ws_size,
                              hipStream_t stream) {
  const float* z1 = (const float*)d_in[0];
  const float* z2 = (const float*)d_in[1];
  const float* W1 = (const float*)d_in[2];
  const float* b1 = (const float*)d_in[3];
  const float* W2 = (const float*)d_in[4];
  const float* b2 = (const float*)d_in[5];
  float* out = (float*)d_out;

  char* ws = (char*)d_ws;
  u16*   Zb    = (u16*)(ws);                          // 8 MB (reused as Mb)
  u16*   H1b   = (u16*)(ws + (8u << 20));             // 8 MB
  float* Hf    = (float*)(ws + (16u << 20));          // 16 MB
  u16*   W1b   = (u16*)(ws + (32u << 20));            // 128 KB
  u16*   W2b   = (u16*)(ws + (32u << 20) + 131072);   // 128 KB
  float* rsum  = (float*)(ws + (32u << 20) + 262144); // 64 KB
  float* snorm = (float*)(ws + (32u << 20) + 262144 + 65536); // 64 KB
  u16*   Mb    = Zb;  // Zb dead after layer 1

  int n4z = Nn * Dd / 4;
  cast4_kernel<<<(n4z + 255) / 256, 256, 0, stream>>>(z1, Zb, n4z);
  cast4_kernel<<<(n4z + 255) / 256, 256, 0, stream>>>(z2, Zb + (size_t)Nn * Dd, n4z);
  int n4w = 256 * 256 / 4;
  cast4_kernel<<<(n4w + 255) / 256, 256, 0, stream>>>(W1, W1b, n4w);
  cast4_kernel<<<(n4w + 255) / 256, 256, 0, stream>>>(W2, W2b, n4w);

  // layer 1: elu(Z @ W1^T + b1) -> bf16
  mfma_gemm_nt<0><<<dim3(TWO_N / 128, 2), 256, 0, stream>>>(Zb, W1b, b1, (void*)H1b, 256, 256);
  // layer 2: H1 @ W2^T + b2 -> f32
  mfma_gemm_nt<1><<<dim3(TWO_N / 128, 2), 256, 0, stream>>>(H1b, W2b, b2, (void*)Hf, 256, 256);

  normalize_rows<<<TWO_N, 64, 0, stream>>>(Hf, Mb, snorm);

  hipMemsetAsync(rsum, 0, TWO_N * sizeof(float), stream);
  // upper-triangle tile pairs: 64 superrows x 129 tiles each = 8256 blocks
  gram_sym<<<dim3(129, 64), 256, 0, stream>>>(Mb, rsum);

  final_loss<<<Nn, 64, 0, stream>>>(Mb, rsum, snorm, out);
}

// Round 4
// 240.290 us; speedup vs baseline: 1.5550x; 1.1560x over previous
//
#include <hip/hip_runtime.h>
#include <hip/hip_bf16.h>
#include <stdint.h>

#define Nn 8192
#define Dd 256
#define TWO_N 16384
#define INV_TAU 2.0f

typedef unsigned short u16;
typedef __bf16 bf16x8 __attribute__((ext_vector_type(8)));
typedef float f32x4 __attribute__((ext_vector_type(4)));

typedef const __attribute__((address_space(1))) void* gas_ptr;
typedef __attribute__((address_space(3))) void* las_ptr;

__device__ __forceinline__ void async_copy16(const void* g, void* l) {
  __builtin_amdgcn_global_load_lds((gas_ptr)g, (las_ptr)l, 16, 0, 0);
}

__device__ __forceinline__ u16 f2bf(float x) {
  uint32_t u = __float_as_uint(x);
  u = u + 0x7fffu + ((u >> 16) & 1u);
  return (u16)(u >> 16);
}
__device__ __forceinline__ float bf2f(u16 u) {
  return __uint_as_float(((uint32_t)u) << 16);
}

// ---------------- fused cast fp32 -> bf16 for z1, z2, W1, W2 ------------------
// quad segments: z1 [0,524288) ; z2 [524288,1048576) ; W1 [1048576,1064960) ; W2 [1064960,1081344)
__global__ void cast_all(const float* __restrict__ z1, const float* __restrict__ z2,
                         const float* __restrict__ W1, const float* __restrict__ W2,
                         u16* __restrict__ Zb, u16* __restrict__ W1b, u16* __restrict__ W2b) {
  int i = blockIdx.x * 256 + threadIdx.x;
  const float4* src; ushort4* dst; int off;
  if (i < 524288)       { src = (const float4*)z1; dst = (ushort4*)Zb;                      off = i; }
  else if (i < 1048576) { src = (const float4*)z2; dst = (ushort4*)(Zb + (size_t)Nn * Dd);  off = i - 524288; }
  else if (i < 1064960) { src = (const float4*)W1; dst = (ushort4*)W1b;                     off = i - 1048576; }
  else                  { src = (const float4*)W2; dst = (ushort4*)W2b;                     off = i - 1064960; }
  float4 v = src[off];
  ushort4 o;
  o.x = f2bf(v.x); o.y = f2bf(v.y); o.z = f2bf(v.z); o.w = f2bf(v.w);
  dst[off] = o;
}

// ---------------- MLP layer GEMM: out[m,n] = sum_k A[m,k]*B[n,k] + bias[n] ----
// LDS layout: granule p of row r holds global granule (p ^ (r&7)) -> conflict-free
template<int EPI>
__global__ __launch_bounds__(256)
void mfma_gemm_nt(const u16* __restrict__ A, const u16* __restrict__ B,
                  const float* __restrict__ bias, void* __restrict__ outp,
                  int K, int Ncols) {
  __shared__ __bf16 sA[128 * 64];
  __shared__ __bf16 sB[128 * 64];
  const int i0 = blockIdx.x * 128;
  const int j0 = blockIdx.y * 128;
  const int t = threadIdx.x;
  const int lane = t & 63, wave = t >> 6;
  const int wm = (wave >> 1) * 64, wn = (wave & 1) * 64;
  const int fr = lane >> 4, fc = lane & 15;
  const int sw = fc & 7;

  f32x4 acc[4][4];
#pragma unroll
  for (int a = 0; a < 4; a++)
#pragma unroll
    for (int b = 0; b < 4; b++) acc[a][b] = (f32x4){0.f, 0.f, 0.f, 0.f};

  const u16* Ag = A + (size_t)i0 * K;
  const u16* Bg = B + (size_t)j0 * K;

  for (int k0 = 0; k0 < K; k0 += 64) {
    __syncthreads();
#pragma unroll
    for (int it = 0; it < 4; ++it) {
      int c = t + 256 * it;
      int row = c >> 3;
      int kc = ((c & 7) ^ (row & 7)) * 8;
      async_copy16(Ag + (size_t)row * K + k0 + kc, (void*)&sA[c * 8]);
      async_copy16(Bg + (size_t)row * K + k0 + kc, (void*)&sB[c * 8]);
    }
    __syncthreads();
#pragma unroll
    for (int ks = 0; ks < 2; ++ks) {
      bf16x8 af[4], bfr[4];
#pragma unroll
      for (int mi = 0; mi < 4; mi++)
        af[mi] = *(const bf16x8*)&sA[(wm + mi * 16 + fc) * 64 + (((ks * 4 + fr) ^ sw) * 8)];
#pragma unroll
      for (int ni = 0; ni < 4; ni++)
        bfr[ni] = *(const bf16x8*)&sB[(wn + ni * 16 + fc) * 64 + (((ks * 4 + fr) ^ sw) * 8)];
#pragma unroll
      for (int mi = 0; mi < 4; mi++)
#pragma unroll
        for (int ni = 0; ni < 4; ni++)
          acc[mi][ni] = __builtin_amdgcn_mfma_f32_16x16x32_bf16(af[mi], bfr[ni], acc[mi][ni], 0, 0, 0);
    }
  }

#pragma unroll
  for (int mi = 0; mi < 4; mi++) {
#pragma unroll
    for (int ni = 0; ni < 4; ni++) {
      int col = j0 + wn + ni * 16 + fc;
      float bv = bias[col];
#pragma unroll
      for (int r = 0; r < 4; r++) {
        int row = i0 + wm + mi * 16 + fr * 4 + r;
        float v = acc[mi][ni][r] + bv;
        if (EPI == 0) {
          v = v > 0.f ? v : (__expf(v) - 1.f);
          ((u16*)outp)[(size_t)row * Ncols + col] = f2bf(v);
        } else {
          ((float*)outp)[(size_t)row * Ncols + col] = v;
        }
      }
    }
  }
}

// ---------------- row-normalize -> bf16 M, plus snorm (4 rows / block) --------
__global__ void normalize_rows(const float* __restrict__ H, u16* __restrict__ Mb,
                               float* __restrict__ snorm) {
  int row = blockIdx.x * 4 + (threadIdx.x >> 6);
  int lane = threadIdx.x & 63;
  float4 v = ((const float4*)(H + (size_t)row * 256))[lane];
  float ss = v.x * v.x + v.y * v.y + v.z * v.z + v.w * v.w;
#pragma unroll
  for (int off = 32; off; off >>= 1) ss += __shfl_xor(ss, off, 64);
  float rn = 1.f / fmaxf(sqrtf(ss), 1e-12f);
  ushort4 o;
  o.x = f2bf(v.x * rn); o.y = f2bf(v.y * rn); o.z = f2bf(v.z * rn); o.w = f2bf(v.w * rn);
  ((ushort4*)(Mb + (size_t)row * 256))[lane] = o;
  float a0 = bf2f(o.x), a1 = bf2f(o.y), a2 = bf2f(o.z), a3 = bf2f(o.w);
  float s2 = a0 * a0 + a1 * a1 + a2 * a2 + a3 * a3;
#pragma unroll
  for (int off = 32; off; off >>= 1) s2 += __shfl_xor(s2, off, 64);
  if (lane == 0) snorm[row] = s2;
}

// ---------------- symmetric Gram-exp-rowsum, strip version --------------------
// Upper triangle of the 128x128 tile grid, strips of up to 4 consecutive j-tiles
// per block (A rows fixed within a strip). Band mapping: row with k tiles
// (k = 128 - i_t) has ceil(k/4) strips; band b = rows with k in [4b+1, 4b+8/..],
// strips/row = b+1, 4 rows/band, cumulative 2b(b+1). Total 2112 blocks,
// dispatched long-strips-first (index reversal).
__global__ __launch_bounds__(256)
void gram_sym(const u16* __restrict__ Mb, float* __restrict__ rsum) {
  __shared__ __bf16 sA[128 * 64];
  __shared__ __bf16 sB[128 * 64];
  const int t = threadIdx.x;
  const int lane = t & 63, wave = t >> 6;
  const int wm = (wave >> 1) * 64, wn = (wave & 1) * 64;
  const int fr = lane >> 4, fc = lane & 15;
  const int sw = fc & 7;

  // ---- strip mapping ----
  int f = 2111 - blockIdx.x;
  int b = 0;
  while (f >= 2 * (b + 1) * (b + 2)) ++b;     // <=31 iterations, uniform
  int rem = f - 2 * b * (b + 1);
  int r = rem / (b + 1);
  int q = rem - r * (b + 1);
  int k = 4 * b + 1 + r;                      // tiles in this row
  const int i_t = 128 - k;
  const int jt0 = i_t + 4 * q;
  const int L = min(4, k - 4 * q);

  const int i0 = i_t * 128;
  const u16* Ag = Mb + (size_t)i0 * 256;

  for (int jt = 0; jt < L; ++jt) {
    const int j_t = jt0 + jt;
    const int j0 = j_t * 128;
    const u16* Bg = Mb + (size_t)j0 * 256;

    f32x4 acc[4][4];
#pragma unroll
    for (int a = 0; a < 4; a++)
#pragma unroll
      for (int bb = 0; bb < 4; bb++) acc[a][bb] = (f32x4){0.f, 0.f, 0.f, 0.f};

    for (int k0 = 0; k0 < 256; k0 += 64) {
      __syncthreads();
#pragma unroll
      for (int it = 0; it < 4; ++it) {
        int c = t + 256 * it;
        int row = c >> 3;
        int kc = ((c & 7) ^ (row & 7)) * 8;
        async_copy16(Ag + (size_t)row * 256 + k0 + kc, (void*)&sA[c * 8]);
        async_copy16(Bg + (size_t)row * 256 + k0 + kc, (void*)&sB[c * 8]);
      }
      __syncthreads();
#pragma unroll
      for (int ks = 0; ks < 2; ++ks) {
        bf16x8 af[4], bfr[4];
#pragma unroll
        for (int mi = 0; mi < 4; mi++)
          af[mi] = *(const bf16x8*)&sA[(wm + mi * 16 + fc) * 64 + (((ks * 4 + fr) ^ sw) * 8)];
#pragma unroll
        for (int ni = 0; ni < 4; ni++)
          bfr[ni] = *(const bf16x8*)&sB[(wn + ni * 16 + fc) * 64 + (((ks * 4 + fr) ^ sw) * 8)];
#pragma unroll
        for (int mi = 0; mi < 4; mi++)
#pragma unroll
          for (int ni = 0; ni < 4; ni++)
            acc[mi][ni] = __builtin_amdgcn_mfma_f32_16x16x32_bf16(af[mi], bfr[ni], acc[mi][ni], 0, 0, 0);
      }
    }

    // epilogue: e = exp(2*s); row-sums -> rows I; col-sums -> rows J (if i!=j)
    float colp[4] = {0.f, 0.f, 0.f, 0.f};
#pragma unroll
    for (int mi = 0; mi < 4; mi++) {
      float rowp0 = 0.f, rowp1 = 0.f, rowp2 = 0.f, rowp3 = 0.f;
#pragma unroll
      for (int ni = 0; ni < 4; ni++) {
        float e0 = __expf(acc[mi][ni][0] * INV_TAU);
        float e1 = __expf(acc[mi][ni][1] * INV_TAU);
        float e2 = __expf(acc[mi][ni][2] * INV_TAU);
        float e3 = __expf(acc[mi][ni][3] * INV_TAU);
        rowp0 += e0; rowp1 += e1; rowp2 += e2; rowp3 += e3;
        colp[ni] += e0 + e1 + e2 + e3;
      }
#pragma unroll
      for (int off = 1; off < 16; off <<= 1) {
        rowp0 += __shfl_xor(rowp0, off, 16);
        rowp1 += __shfl_xor(rowp1, off, 16);
        rowp2 += __shfl_xor(rowp2, off, 16);
        rowp3 += __shfl_xor(rowp3, off, 16);
      }
      if (fc == 0) {
        int rbase = i0 + wm + mi * 16 + fr * 4;
        atomicAdd(&rsum[rbase + 0], rowp0);
        atomicAdd(&rsum[rbase + 1], rowp1);
        atomicAdd(&rsum[rbase + 2], rowp2);
        atomicAdd(&rsum[rbase + 3], rowp3);
      }
    }

    if (j_t != i_t) {
#pragma unroll
      for (int ni = 0; ni < 4; ni++) {
        float v = colp[ni];
        v += __shfl_xor(v, 16, 64);
        v += __shfl_xor(v, 32, 64);
        if (fr == 0) atomicAdd(&rsum[j0 + wn + ni * 16 + fc], v);
      }
    }
  }
}

// ---------------- final loss (4 rows / block) --------------------------------
__global__ void final_loss(const u16* __restrict__ Mb, const float* __restrict__ rsum,
                           const float* __restrict__ snorm, float* __restrict__ out) {
  int i = blockIdx.x * 4 + (threadIdx.x >> 6);
  int lane = threadIdx.x & 63;
  ushort4 ua = ((const ushort4*)(Mb + (size_t)i * 256))[lane];
  ushort4 ub = ((const ushort4*)(Mb + (size_t)(Nn + i) * 256))[lane];
  float d = bf2f(ua.x) * bf2f(ub.x) + bf2f(ua.y) * bf2f(ub.y) +
            bf2f(ua.z) * bf2f(ub.z) + bf2f(ua.w) * bf2f(ub.w);
#pragma unroll
  for (int off = 32; off; off >>= 1) d += __shfl_xor(d, off, 64);
  if (lane == 0) {
    float den1 = rsum[i] - __expf(snorm[i] * INV_TAU);
    float den2 = rsum[Nn + i] - __expf(snorm[Nn + i] * INV_TAU);
    out[i] = 0.5f * (logf(den1) + logf(den2)) - d * INV_TAU;
  }
}

extern "C" void kernel_launch(void* const* d_in, const int* in_sizes, int n_in,
                              void* d_out, int out_size, void* d_ws, size_t ws_size,
                              hipStream_t stream) {
  const float* z1 = (const float*)d_in[0];
  const float* z2 = (const float*)d_in[1];
  const float* W1 = (const float*)d_in[2];
  const float* b1 = (const float*)d_in[3];
  const float* W2 = (const float*)d_in[4];
  const float* b2 = (const float*)d_in[5];
  float* out = (float*)d_out;

  char* ws = (char*)d_ws;
  u16*   Zb    = (u16*)(ws);                          // 8 MB (reused as Mb)
  u16*   H1b   = (u16*)(ws + (8u << 20));             // 8 MB
  float* Hf    = (float*)(ws + (16u << 20));          // 16 MB
  u16*   W1b   = (u16*)(ws + (32u << 20));            // 128 KB
  u16*   W2b   = (u16*)(ws + (32u << 20) + 131072);   // 128 KB
  float* rsum  = (float*)(ws + (32u << 20) + 262144); // 64 KB
  float* snorm = (float*)(ws + (32u << 20) + 262144 + 65536); // 64 KB
  u16*   Mb    = Zb;  // Zb dead after layer 1

  // fused casts: 1081344 quads total
  cast_all<<<1081344 / 256, 256, 0, stream>>>(z1, z2, W1, W2, Zb, W1b, W2b);

  // layer 1: elu(Z @ W1^T + b1) -> bf16
  mfma_gemm_nt<0><<<dim3(TWO_N / 128, 2), 256, 0, stream>>>(Zb, W1b, b1, (void*)H1b, 256, 256);
  // layer 2: H1 @ W2^T + b2 -> f32
  mfma_gemm_nt<1><<<dim3(TWO_N / 128, 2), 256, 0, stream>>>(H1b, W2b, b2, (void*)Hf, 256, 256);

  normalize_rows<<<TWO_N / 4, 256, 0, stream>>>(Hf, Mb, snorm);

  hipMemsetAsync(rsum, 0, TWO_N * sizeof(float), stream);
  // upper-triangle strips of <=4 tiles: 2112 blocks, long strips first
  gram_sym<<<2112, 256, 0, stream>>>(Mb, rsum);

  final_loss<<<Nn / 4, 256, 0, stream>>>(Mb, rsum, snorm, out);
}

// Round 5
// 210.455 us; speedup vs baseline: 1.7755x; 1.1418x over previous
//
#include <hip/hip_runtime.h>
#include <hip/hip_bf16.h>
#include <stdint.h>

#define Nn 8192
#define Dd 256
#define TWO_N 16384
#define INV_TAU 2.0f

typedef unsigned short u16;
typedef __bf16 bf16x8 __attribute__((ext_vector_type(8)));
typedef float f32x4 __attribute__((ext_vector_type(4)));

typedef const __attribute__((address_space(1))) void* gas_ptr;
typedef __attribute__((address_space(3))) void* las_ptr;

__device__ __forceinline__ void async_copy16(const void* g, void* l) {
  __builtin_amdgcn_global_load_lds((gas_ptr)g, (las_ptr)l, 16, 0, 0);
}

__device__ __forceinline__ u16 f2bf(float x) {
  uint32_t u = __float_as_uint(x);
  u = u + 0x7fffu + ((u >> 16) & 1u);
  return (u16)(u >> 16);
}
__device__ __forceinline__ float bf2f(u16 u) {
  return __uint_as_float(((uint32_t)u) << 16);
}

// ---------------- fused cast fp32 -> bf16 (+ rsum zero-init) ------------------
__global__ void cast_all(const float* __restrict__ z1, const float* __restrict__ z2,
                         const float* __restrict__ W1, const float* __restrict__ W2,
                         u16* __restrict__ Zb, u16* __restrict__ W1b, u16* __restrict__ W2b,
                         float* __restrict__ rsum) {
  int i = blockIdx.x * 256 + threadIdx.x;
  if (i < TWO_N) rsum[i] = 0.f;
  const float4* src; ushort4* dst; int off;
  if (i < 524288)       { src = (const float4*)z1; dst = (ushort4*)Zb;                      off = i; }
  else if (i < 1048576) { src = (const float4*)z2; dst = (ushort4*)(Zb + (size_t)Nn * Dd);  off = i - 524288; }
  else if (i < 1064960) { src = (const float4*)W1; dst = (ushort4*)W1b;                     off = i - 1048576; }
  else                  { src = (const float4*)W2; dst = (ushort4*)W2b;                     off = i - 1064960; }
  float4 v = src[off];
  ushort4 o;
  o.x = f2bf(v.x); o.y = f2bf(v.y); o.z = f2bf(v.z); o.w = f2bf(v.w);
  dst[off] = o;
}

// ---------------- MLP layer GEMM: out[m,n] = sum_k A[m,k]*B[n,k] + bias[n] ----
template<int EPI>
__global__ __launch_bounds__(256)
void mfma_gemm_nt(const u16* __restrict__ A, const u16* __restrict__ B,
                  const float* __restrict__ bias, void* __restrict__ outp,
                  int K, int Ncols) {
  __shared__ __bf16 sA[128 * 64];
  __shared__ __bf16 sB[128 * 64];
  const int i0 = blockIdx.x * 128;
  const int j0 = blockIdx.y * 128;
  const int t = threadIdx.x;
  const int lane = t & 63, wave = t >> 6;
  const int wm = (wave >> 1) * 64, wn = (wave & 1) * 64;
  const int fr = lane >> 4, fc = lane & 15;
  const int sw = fc & 7;

  f32x4 acc[4][4];
#pragma unroll
  for (int a = 0; a < 4; a++)
#pragma unroll
    for (int b = 0; b < 4; b++) acc[a][b] = (f32x4){0.f, 0.f, 0.f, 0.f};

  const u16* Ag = A + (size_t)i0 * K;
  const u16* Bg = B + (size_t)j0 * K;

  for (int k0 = 0; k0 < K; k0 += 64) {
    __syncthreads();
#pragma unroll
    for (int it = 0; it < 4; ++it) {
      int c = t + 256 * it;
      int row = c >> 3;
      int kc = ((c & 7) ^ (row & 7)) * 8;
      async_copy16(Ag + (size_t)row * K + k0 + kc, (void*)&sA[c * 8]);
      async_copy16(Bg + (size_t)row * K + k0 + kc, (void*)&sB[c * 8]);
    }
    __syncthreads();
#pragma unroll
    for (int ks = 0; ks < 2; ++ks) {
      bf16x8 af[4], bfr[4];
#pragma unroll
      for (int mi = 0; mi < 4; mi++)
        af[mi] = *(const bf16x8*)&sA[(wm + mi * 16 + fc) * 64 + (((ks * 4 + fr) ^ sw) * 8)];
#pragma unroll
      for (int ni = 0; ni < 4; ni++)
        bfr[ni] = *(const bf16x8*)&sB[(wn + ni * 16 + fc) * 64 + (((ks * 4 + fr) ^ sw) * 8)];
#pragma unroll
      for (int mi = 0; mi < 4; mi++)
#pragma unroll
        for (int ni = 0; ni < 4; ni++)
          acc[mi][ni] = __builtin_amdgcn_mfma_f32_16x16x32_bf16(af[mi], bfr[ni], acc[mi][ni], 0, 0, 0);
    }
  }

#pragma unroll
  for (int mi = 0; mi < 4; mi++) {
#pragma unroll
    for (int ni = 0; ni < 4; ni++) {
      int col = j0 + wn + ni * 16 + fc;
      float bv = bias[col];
#pragma unroll
      for (int r = 0; r < 4; r++) {
        int row = i0 + wm + mi * 16 + fr * 4 + r;
        float v = acc[mi][ni][r] + bv;
        if (EPI == 0) {
          v = v > 0.f ? v : (__expf(v) - 1.f);
          ((u16*)outp)[(size_t)row * Ncols + col] = f2bf(v);
        } else {
          ((float*)outp)[(size_t)row * Ncols + col] = v;
        }
      }
    }
  }
}

// ---------------- row-normalize -> bf16 M, plus snorm (4 rows / block) --------
__global__ void normalize_rows(const float* __restrict__ H, u16* __restrict__ Mb,
                               float* __restrict__ snorm) {
  int row = blockIdx.x * 4 + (threadIdx.x >> 6);
  int lane = threadIdx.x & 63;
  float4 v = ((const float4*)(H + (size_t)row * 256))[lane];
  float ss = v.x * v.x + v.y * v.y + v.z * v.z + v.w * v.w;
#pragma unroll
  for (int off = 32; off; off >>= 1) ss += __shfl_xor(ss, off, 64);
  float rn = 1.f / fmaxf(sqrtf(ss), 1e-12f);
  ushort4 o;
  o.x = f2bf(v.x * rn); o.y = f2bf(v.y * rn); o.z = f2bf(v.z * rn); o.w = f2bf(v.w * rn);
  ((ushort4*)(Mb + (size_t)row * 256))[lane] = o;
  float a0 = bf2f(o.x), a1 = bf2f(o.y), a2 = bf2f(o.z), a3 = bf2f(o.w);
  float s2 = a0 * a0 + a1 * a1 + a2 * a2 + a3 * a3;
#pragma unroll
  for (int off = 32; off; off >>= 1) s2 += __shfl_xor(s2, off, 64);
  if (lane == 0) snorm[row] = s2;
}

// ---------------- symmetric Gram-exp-rowsum, A-resident strip version ---------
// A strip (128 rows x 256 K, 64KB) persists in LDS across <=4 j-tiles.
// Per k0-step only the 16KB B chunk is staged -> half the barrier drain.
// LDS 80KB => 2 blocks/CU is the occupancy bound, so VGPRs are free:
// row-sum partials stay in registers across the strip (reduced once at end).
__global__ __launch_bounds__(256, 2)
void gram_sym(const u16* __restrict__ Mb, float* __restrict__ rsum) {
  __shared__ __bf16 sA[128 * 256];   // 64 KB, persistent per strip
  __shared__ __bf16 sB[128 * 64];    // 16 KB, per k0-chunk
  const int t = threadIdx.x;
  const int lane = t & 63, wave = t >> 6;
  const int wm = (wave >> 1) * 64, wn = (wave & 1) * 64;
  const int fr = lane >> 4, fc = lane & 15;
  const int sw = fc & 7;

  // ---- strip mapping (band closed form), long strips dispatched first ----
  int f = 2111 - blockIdx.x;
  int b = 0;
  while (f >= 2 * (b + 1) * (b + 2)) ++b;
  int rem = f - 2 * b * (b + 1);
  int r = rem / (b + 1);
  int q = rem - r * (b + 1);
  int k = 4 * b + 1 + r;
  const int i_t = 128 - k;
  const int jt0 = i_t + 4 * q;
  const int L = min(4, k - 4 * q);

  const int i0 = i_t * 128;
  const u16* Ag = Mb + (size_t)i0 * 256;

  // stage full A strip: 128 rows x 32 granules, swizzled within 8-granule groups
#pragma unroll
  for (int it = 0; it < 16; ++it) {
    int c = t + 256 * it;
    int row = c >> 5, pos = c & 31;
    int g = (pos & 24) | ((pos & 7) ^ (row & 7));
    async_copy16(Ag + (size_t)row * 256 + g * 8, (void*)&sA[c * 8]);
  }

  float rowacc[4][4];
#pragma unroll
  for (int a = 0; a < 4; a++)
#pragma unroll
    for (int rr = 0; rr < 4; rr++) rowacc[a][rr] = 0.f;

  for (int jt = 0; jt < L; ++jt) {
    const int j_t = jt0 + jt;
    const int j0 = j_t * 128;
    const u16* Bg = Mb + (size_t)j0 * 256;

    f32x4 acc[4][4];
#pragma unroll
    for (int a = 0; a < 4; a++)
#pragma unroll
      for (int bb = 0; bb < 4; bb++) acc[a][bb] = (f32x4){0.f, 0.f, 0.f, 0.f};

    for (int k0 = 0; k0 < 256; k0 += 64) {
      __syncthreads();   // sB safe to overwrite
#pragma unroll
      for (int it = 0; it < 4; ++it) {
        int c = t + 256 * it;
        int row = c >> 3;
        int kc = ((c & 7) ^ (row & 7)) * 8;
        async_copy16(Bg + (size_t)row * 256 + k0 + kc, (void*)&sB[c * 8]);
      }
      __syncthreads();   // B (and, first pass, A) resident
      const int kgb = k0 >> 3;
#pragma unroll
      for (int ks = 0; ks < 2; ++ks) {
        bf16x8 af[4], bfr[4];
#pragma unroll
        for (int mi = 0; mi < 4; mi++)
          af[mi] = *(const bf16x8*)&sA[(wm + mi * 16 + fc) * 256 + (kgb + (((ks * 4 + fr) ^ sw))) * 8];
#pragma unroll
        for (int ni = 0; ni < 4; ni++)
          bfr[ni] = *(const bf16x8*)&sB[(wn + ni * 16 + fc) * 64 + (((ks * 4 + fr) ^ sw) * 8)];
#pragma unroll
        for (int mi = 0; mi < 4; mi++)
#pragma unroll
          for (int ni = 0; ni < 4; ni++)
            acc[mi][ni] = __builtin_amdgcn_mfma_f32_16x16x32_bf16(af[mi], bfr[ni], acc[mi][ni], 0, 0, 0);
      }
    }

    // epilogue: e = exp(2*s); accumulate row partials in regs; col-sums per tile
    float colp[4] = {0.f, 0.f, 0.f, 0.f};
#pragma unroll
    for (int mi = 0; mi < 4; mi++) {
#pragma unroll
      for (int ni = 0; ni < 4; ni++) {
        float e0 = __expf(acc[mi][ni][0] * INV_TAU);
        float e1 = __expf(acc[mi][ni][1] * INV_TAU);
        float e2 = __expf(acc[mi][ni][2] * INV_TAU);
        float e3 = __expf(acc[mi][ni][3] * INV_TAU);
        rowacc[mi][0] += e0; rowacc[mi][1] += e1;
        rowacc[mi][2] += e2; rowacc[mi][3] += e3;
        colp[ni] += e0 + e1 + e2 + e3;
      }
    }
    if (j_t != i_t) {
#pragma unroll
      for (int ni = 0; ni < 4; ni++) {
        float v = colp[ni];
        v += __shfl_xor(v, 16, 64);
        v += __shfl_xor(v, 32, 64);
        if (fr == 0) atomicAdd(&rsum[j0 + wn + ni * 16 + fc], v);
      }
    }
  }

  // strip-end: row-sum reduce across the 16 fc lanes, one atomic set
#pragma unroll
  for (int mi = 0; mi < 4; mi++) {
#pragma unroll
    for (int rr = 0; rr < 4; rr++) {
      float v = rowacc[mi][rr];
#pragma unroll
      for (int off = 1; off < 16; off <<= 1) v += __shfl_xor(v, off, 16);
      rowacc[mi][rr] = v;
    }
  }
  if (fc == 0) {
#pragma unroll
    for (int mi = 0; mi < 4; mi++) {
      int rbase = i0 + wm + mi * 16 + fr * 4;
      atomicAdd(&rsum[rbase + 0], rowacc[mi][0]);
      atomicAdd(&rsum[rbase + 1], rowacc[mi][1]);
      atomicAdd(&rsum[rbase + 2], rowacc[mi][2]);
      atomicAdd(&rsum[rbase + 3], rowacc[mi][3]);
    }
  }
}

// ---------------- final loss (4 rows / block) --------------------------------
__global__ void final_loss(const u16* __restrict__ Mb, const float* __restrict__ rsum,
                           const float* __restrict__ snorm, float* __restrict__ out) {
  int i = blockIdx.x * 4 + (threadIdx.x >> 6);
  int lane = threadIdx.x & 63;
  ushort4 ua = ((const ushort4*)(Mb + (size_t)i * 256))[lane];
  ushort4 ub = ((const ushort4*)(Mb + (size_t)(Nn + i) * 256))[lane];
  float d = bf2f(ua.x) * bf2f(ub.x) + bf2f(ua.y) * bf2f(ub.y) +
            bf2f(ua.z) * bf2f(ub.z) + bf2f(ua.w) * bf2f(ub.w);
#pragma unroll
  for (int off = 32; off; off >>= 1) d += __shfl_xor(d, off, 64);
  if (lane == 0) {
    float den1 = rsum[i] - __expf(snorm[i] * INV_TAU);
    float den2 = rsum[Nn + i] - __expf(snorm[Nn + i] * INV_TAU);
    out[i] = 0.5f * (logf(den1) + logf(den2)) - d * INV_TAU;
  }
}

extern "C" void kernel_launch(void* const* d_in, const int* in_sizes, int n_in,
                              void* d_out, int out_size, void* d_ws, size_t ws_size,
                              hipStream_t stream) {
  const float* z1 = (const float*)d_in[0];
  const float* z2 = (const float*)d_in[1];
  const float* W1 = (const float*)d_in[2];
  const float* b1 = (const float*)d_in[3];
  const float* W2 = (const float*)d_in[4];
  const float* b2 = (const float*)d_in[5];
  float* out = (float*)d_out;

  char* ws = (char*)d_ws;
  u16*   Zb    = (u16*)(ws);                          // 8 MB (reused as Mb)
  u16*   H1b   = (u16*)(ws + (8u << 20));             // 8 MB
  float* Hf    = (float*)(ws + (16u << 20));          // 16 MB
  u16*   W1b   = (u16*)(ws + (32u << 20));            // 128 KB
  u16*   W2b   = (u16*)(ws + (32u << 20) + 131072);   // 128 KB
  float* rsum  = (float*)(ws + (32u << 20) + 262144); // 64 KB
  float* snorm = (float*)(ws + (32u << 20) + 262144 + 65536); // 64 KB
  u16*   Mb    = Zb;  // Zb dead after layer 1

  // fused casts (+ rsum zeroing): 1081344 quads total
  cast_all<<<1081344 / 256, 256, 0, stream>>>(z1, z2, W1, W2, Zb, W1b, W2b, rsum);

  // layer 1: elu(Z @ W1^T + b1) -> bf16
  mfma_gemm_nt<0><<<dim3(TWO_N / 128, 2), 256, 0, stream>>>(Zb, W1b, b1, (void*)H1b, 256, 256);
  // layer 2: H1 @ W2^T + b2 -> f32
  mfma_gemm_nt<1><<<dim3(TWO_N / 128, 2), 256, 0, stream>>>(H1b, W2b, b2, (void*)Hf, 256, 256);

  normalize_rows<<<TWO_N / 4, 256, 0, stream>>>(Hf, Mb, snorm);

  // upper-triangle strips of <=4 tiles: 2112 blocks, long strips first
  gram_sym<<<2112, 256, 0, stream>>>(Mb, rsum);

  final_loss<<<Nn / 4, 256, 0, stream>>>(Mb, rsum, snorm, out);
}